// Round 1
// baseline (554.257 us; speedup 1.0000x reference)
//
#include <hip/hip_runtime.h>
#include <math.h>

#define S_LEN  16384
#define NCONV  128
#define NBATCH 256
#define TPB    256

// Metadata arrays may arrive as int64 (np.int64) or int32. Values are small
// positive ints, so if int64: dword[2*i+1]==0 always; probe ks dword[1].
__device__ __forceinline__ int geti(const int* __restrict__ a, int i, int is64) {
  return is64 ? a[2 * i] : a[i];
}

template <int K>
__device__ __forceinline__ void conv_row(
    const float* __restrict__ xrow, const float* __restrict__ w, float bval,
    int d, int p, int L, int tid, float& mx, int& cnt)
{
  const int jhi = L - p;  // interior: j in [p, jhi) -> all taps in-bounds
  int base = p;

  // Interior, 4-way strided register blocking. Each load instr is lane-stride-1
  // (perfectly coalesced); the u*TPB offsets become immediate offsets.
  for (; base + TPB * 4 <= jhi; base += TPB * 4) {
    const float* xp = xrow + (base + tid - p);
    float a0 = bval, a1 = bval, a2 = bval, a3 = bval;
#pragma unroll
    for (int t = 0; t < K; ++t) {
      const float* q = xp + t * d;
      a0 = fmaf(w[t], q[0 * TPB], a0);
      a1 = fmaf(w[t], q[1 * TPB], a1);
      a2 = fmaf(w[t], q[2 * TPB], a2);
      a3 = fmaf(w[t], q[3 * TPB], a3);
    }
    mx = fmaxf(mx, fmaxf(fmaxf(a0, a1), fmaxf(a2, a3)));
    cnt += (a0 >= 0.f) + (a1 >= 0.f) + (a2 >= 0.f) + (a3 >= 0.f);
  }
  // Interior remainder
  for (int j = base + tid; j < jhi; j += TPB) {
    const float* xp = xrow + (j - p);
    float a = bval;
#pragma unroll
    for (int t = 0; t < K; ++t) a = fmaf(w[t], xp[t * d], a);
    mx = fmaxf(mx, a);
    cnt += (a >= 0.f);
  }
  // Lower boundary [0, p): some taps read the left zero-pad
  for (int j = tid; j < p; j += TPB) {
    const int pos0 = j - p;
    float a = bval;
#pragma unroll
    for (int t = 0; t < K; ++t) {
      const int pos = pos0 + t * d;
      const float v = ((unsigned)pos < (unsigned)S_LEN) ? xrow[pos] : 0.f;
      a = fmaf(w[t], v, a);
    }
    mx = fmaxf(mx, a);
    cnt += (a >= 0.f);
  }
  // Upper boundary [jhi, L): some taps read the right zero-pad
  for (int j = jhi + tid; j < L; j += TPB) {
    const int pos0 = j - p;
    float a = bval;
#pragma unroll
    for (int t = 0; t < K; ++t) {
      const int pos = pos0 + t * d;
      const float v = ((unsigned)pos < (unsigned)S_LEN) ? xrow[pos] : 0.f;
      a = fmaf(w[t], v, a);
    }
    mx = fmaxf(mx, a);
    cnt += (a >= 0.f);
  }
}

__global__ __launch_bounds__(TPB) void rocket_feats(
    const float* __restrict__ x, const float* __restrict__ W,
    const float* __restrict__ bias,
    const int* __restrict__ ks, const int* __restrict__ dil,
    const int* __restrict__ pad, float* __restrict__ out)
{
  const int tid = threadIdx.x;
  const int blk = blockIdx.x;

  // XCD swizzle: round-robin dispatch (blk%8 -> XCD) means, per XCD, conv index
  // cycles fastest over a FIXED batch row -> 64KB row stays hot in that XCD L2
  // across all 128 convs.
  const int xcd  = blk & 7;
  const int slot = blk >> 3;
  const int ci   = slot & (NCONV - 1);
  const int b    = ((slot >> 7) << 3) | xcd;

  const int is64 = (ks[1] == 0);
  const int k = geti(ks, ci, is64);
  const int d = geti(dil, ci, is64);
  const int p = geti(pad, ci, is64);
  const int L = S_LEN + 2 * p - d * (k - 1);
  const float bval = bias[ci];
  const float* xrow = x + (size_t)b * S_LEN;

  float mx = -INFINITY;
  int cnt = 0;

  if (k == 7) {
    float w[7];
#pragma unroll
    for (int t = 0; t < 7; ++t) w[t] = W[ci * 11 + t];
    conv_row<7>(xrow, w, bval, d, p, L, tid, mx, cnt);
  } else if (k == 9) {
    float w[9];
#pragma unroll
    for (int t = 0; t < 9; ++t) w[t] = W[ci * 11 + t];
    conv_row<9>(xrow, w, bval, d, p, L, tid, mx, cnt);
  } else {
    float w[11];
#pragma unroll
    for (int t = 0; t < 11; ++t) w[t] = W[ci * 11 + t];
    conv_row<11>(xrow, w, bval, d, p, L, tid, mx, cnt);
  }

  // Wave-64 butterfly reduce, then cross-wave via LDS.
#pragma unroll
  for (int off = 32; off > 0; off >>= 1) {
    mx = fmaxf(mx, __shfl_down(mx, off, 64));
    cnt += __shfl_down(cnt, off, 64);
  }
  __shared__ float smx[TPB / 64];
  __shared__ int scnt[TPB / 64];
  const int lane = tid & 63, wid = tid >> 6;
  if (lane == 0) { smx[wid] = mx; scnt[wid] = cnt; }
  __syncthreads();
  if (tid == 0) {
    float m = smx[0];
    int c = scnt[0];
#pragma unroll
    for (int ww = 1; ww < TPB / 64; ++ww) { m = fmaxf(m, smx[ww]); c += scnt[ww]; }
    out[(size_t)b * (2 * NCONV) + 2 * ci]     = m;
    out[(size_t)b * (2 * NCONV) + 2 * ci + 1] = (float)c / (float)L;
  }
}

extern "C" void kernel_launch(void* const* d_in, const int* in_sizes, int n_in,
                              void* d_out, int out_size, void* d_ws, size_t ws_size,
                              hipStream_t stream) {
  const float* x    = (const float*)d_in[0];
  const float* W    = (const float*)d_in[1];
  const float* bias = (const float*)d_in[2];
  const int*   ks   = (const int*)d_in[3];
  const int*   dil  = (const int*)d_in[4];
  const int*   pad  = (const int*)d_in[5];
  float* out = (float*)d_out;

  hipLaunchKernelGGL(rocket_feats, dim3(NBATCH * NCONV), dim3(TPB), 0, stream,
                     x, W, bias, ks, dil, pad, out);
}

// Round 2
// 431.005 us; speedup vs baseline: 1.2860x; 1.2860x over previous
//
#include <hip/hip_runtime.h>
#include <math.h>

#define S_LEN  16384
#define NCONV  128
#define NBATCH 256
#define TPB    256

__device__ __forceinline__ int geti(const int* __restrict__ a, int i, int is64) {
  return is64 ? a[2 * i] : a[i];
}

__device__ __forceinline__ float safe_load(const float* __restrict__ xrow, int pos) {
  int cl = min(max(pos, 0), S_LEN - 1);
  float v = xrow[cl];
  return ((unsigned)pos < (unsigned)S_LEN) ? v : 0.f;
}

// ---- class-walk: thread computes outputs j = r + q*d for q in [q0,q1) with a
// K-deep register shift-window (1 load per output instead of K).
// SAFE: bounds-check every load (boundary phases). EXACT: n is a multiple of K
// so tail predication is compiled out (interior phase).
template <int K, bool SAFE, bool EXACT>
__device__ __forceinline__ void walk_class(
    const float* __restrict__ xrow, const float* __restrict__ w, float bval,
    int d, int p, int r, int q0, int q1, float& mx, int& cnt)
{
  const int n = q1 - q0;
  if (n <= 0) return;
  const int sbase = r - p;
  float win[K];
  int pos = sbase + q0 * d;
#pragma unroll
  for (int t = 0; t < K - 1; ++t) {
    win[t] = SAFE ? safe_load(xrow, pos) : xrow[pos];
    pos += d;
  }
  // pos == tap(K-1) position of output q0
  for (int i = 0; i < n; i += K) {
#pragma unroll
    for (int s = 0; s < K; ++s) {
      win[(s + K - 1) % K] = SAFE ? safe_load(xrow, pos) : xrow[pos];
      pos += d;
      float a = bval;
#pragma unroll
      for (int t = 0; t < K; ++t) a = fmaf(w[t], win[(s + t) % K], a);
      if (EXACT || (i + s < n)) { mx = fmaxf(mx, a); cnt += (a >= 0.f); }
    }
  }
}

// Split [q0,q1) into safe-lo / raw-interior (multiple of K) / safe-hi.
template <int K>
__device__ __forceinline__ void walk_class_split(
    const float* __restrict__ xrow, const float* __restrict__ w, float bval,
    int d, int p, int r, int q0, int q1, float& mx, int& cnt)
{
  if (q1 <= q0) return;
  // all-taps-in-bounds q range: tap0 = r-p+q*d >= 0 and tapK-1 <= S_LEN-1
  const int qlo = (p > r) ? (p - r + d - 1) / d : 0;
  const int qhi = (S_LEN - 1 - r + p) / d - (K - 1);  // numerator >= 0 always
  int i0 = min(max(qlo, q0), q1);
  int i1 = min(qhi + 1, q1);
  if (i1 < i0) i1 = i0;
  const int i1a = i0 + ((i1 - i0) / K) * K;
  walk_class<K, true, false>(xrow, w, bval, d, p, r, q0, i0, mx, cnt);
  if (i1a > i0)
    walk_class<K, false, true>(xrow, w, bval, d, p, r, i0, i1a, mx, cnt);
  walk_class<K, true, false>(xrow, w, bval, d, p, r, i1a, q1, mx, cnt);
}

// ---- direct path (used for d < 4 where class-walk scatters): Round-1 scheme.
template <int K>
__device__ __forceinline__ void conv_row(
    const float* __restrict__ xrow, const float* __restrict__ w, float bval,
    int d, int p, int L, int tid, float& mx, int& cnt)
{
  const int jhi = L - p;
  int base = p;
  for (; base + TPB * 4 <= jhi; base += TPB * 4) {
    const float* xp = xrow + (base + tid - p);
    float a0 = bval, a1 = bval, a2 = bval, a3 = bval;
#pragma unroll
    for (int t = 0; t < K; ++t) {
      const float* q = xp + t * d;
      a0 = fmaf(w[t], q[0 * TPB], a0);
      a1 = fmaf(w[t], q[1 * TPB], a1);
      a2 = fmaf(w[t], q[2 * TPB], a2);
      a3 = fmaf(w[t], q[3 * TPB], a3);
    }
    mx = fmaxf(mx, fmaxf(fmaxf(a0, a1), fmaxf(a2, a3)));
    cnt += (a0 >= 0.f) + (a1 >= 0.f) + (a2 >= 0.f) + (a3 >= 0.f);
  }
  for (int j = base + tid; j < jhi; j += TPB) {
    const float* xp = xrow + (j - p);
    float a = bval;
#pragma unroll
    for (int t = 0; t < K; ++t) a = fmaf(w[t], xp[t * d], a);
    mx = fmaxf(mx, a);
    cnt += (a >= 0.f);
  }
  for (int j = tid; j < p; j += TPB) {
    const int pos0 = j - p;
    float a = bval;
#pragma unroll
    for (int t = 0; t < K; ++t) a = fmaf(w[t], safe_load(xrow, pos0 + t * d), a);
    mx = fmaxf(mx, a);
    cnt += (a >= 0.f);
  }
  for (int j = jhi + tid; j < L; j += TPB) {
    const int pos0 = j - p;
    float a = bval;
#pragma unroll
    for (int t = 0; t < K; ++t) a = fmaf(w[t], safe_load(xrow, pos0 + t * d), a);
    mx = fmaxf(mx, a);
    cnt += (a >= 0.f);
  }
}

template <int K>
__device__ __forceinline__ void do_conv(
    const float* __restrict__ xrow, const float* __restrict__ w, float bval,
    int d, int p, int L, int tid, float& mx, int& cnt)
{
  if (d >= 4) {
    if (d >= TPB) {
      // classes >= threads: each thread walks whole classes r = tid, tid+TPB, ...
      for (int r = tid; r < d; r += TPB) {
        if (r >= L) continue;
        const int Q = (L - 1 - r) / d + 1;
        walk_class_split<K>(xrow, w, bval, d, p, r, 0, Q, mx, cnt);
      }
    } else {
      // threads >= classes: split each class's q-range among its threads
      const int r  = tid % d;
      const int v  = tid / d;
      const int nv = (TPB - 1 - r) / d + 1;   // threads on this class
      const int Q  = (L - 1 - r) / d + 1;     // outputs in this class (L > d here)
      const int q0 = (int)(((long long)Q * v) / nv);
      const int q1 = (int)(((long long)Q * (v + 1)) / nv);
      walk_class_split<K>(xrow, w, bval, d, p, r, q0, q1, mx, cnt);
    }
  } else {
    conv_row<K>(xrow, w, bval, d, p, L, tid, mx, cnt);
  }
}

__global__ __launch_bounds__(TPB) void rocket_feats(
    const float* __restrict__ x, const float* __restrict__ W,
    const float* __restrict__ bias,
    const int* __restrict__ ks, const int* __restrict__ dil,
    const int* __restrict__ pad, float* __restrict__ out)
{
  const int tid = threadIdx.x;
  const int blk = blockIdx.x;

  // XCD swizzle: per XCD, conv index cycles fastest over a fixed batch row so
  // the 64KB row stays hot in that XCD's L2 across all 128 convs.
  const int xcd  = blk & 7;
  const int slot = blk >> 3;
  const int ci   = slot & (NCONV - 1);
  const int b    = ((slot >> 7) << 3) | xcd;

  const int is64 = (ks[1] == 0);
  const int k = geti(ks, ci, is64);
  const int d = geti(dil, ci, is64);
  const int p = geti(pad, ci, is64);
  const int L = S_LEN + 2 * p - d * (k - 1);
  const float bval = bias[ci];
  const float* xrow = x + (size_t)b * S_LEN;

  float mx = -INFINITY;
  int cnt = 0;

  if (k == 7) {
    float w[7];
#pragma unroll
    for (int t = 0; t < 7; ++t) w[t] = W[ci * 11 + t];
    do_conv<7>(xrow, w, bval, d, p, L, tid, mx, cnt);
  } else if (k == 9) {
    float w[9];
#pragma unroll
    for (int t = 0; t < 9; ++t) w[t] = W[ci * 11 + t];
    do_conv<9>(xrow, w, bval, d, p, L, tid, mx, cnt);
  } else {
    float w[11];
#pragma unroll
    for (int t = 0; t < 11; ++t) w[t] = W[ci * 11 + t];
    do_conv<11>(xrow, w, bval, d, p, L, tid, mx, cnt);
  }

#pragma unroll
  for (int off = 32; off > 0; off >>= 1) {
    mx = fmaxf(mx, __shfl_down(mx, off, 64));
    cnt += __shfl_down(cnt, off, 64);
  }
  __shared__ float smx[TPB / 64];
  __shared__ int scnt[TPB / 64];
  const int lane = tid & 63, wid = tid >> 6;
  if (lane == 0) { smx[wid] = mx; scnt[wid] = cnt; }
  __syncthreads();
  if (tid == 0) {
    float m = smx[0];
    int c = scnt[0];
#pragma unroll
    for (int ww = 1; ww < TPB / 64; ++ww) { m = fmaxf(m, smx[ww]); c += scnt[ww]; }
    out[(size_t)b * (2 * NCONV) + 2 * ci]     = m;
    out[(size_t)b * (2 * NCONV) + 2 * ci + 1] = (float)c / (float)L;
  }
}

extern "C" void kernel_launch(void* const* d_in, const int* in_sizes, int n_in,
                              void* d_out, int out_size, void* d_ws, size_t ws_size,
                              hipStream_t stream) {
  const float* x    = (const float*)d_in[0];
  const float* W    = (const float*)d_in[1];
  const float* bias = (const float*)d_in[2];
  const int*   ks   = (const int*)d_in[3];
  const int*   dil  = (const int*)d_in[4];
  const int*   pad  = (const int*)d_in[5];
  float* out = (float*)d_out;

  hipLaunchKernelGGL(rocket_feats, dim3(NBATCH * NCONV), dim3(TPB), 0, stream,
                     x, W, bias, ks, dil, pad, out);
}